// Round 13
// baseline (418.388 us; speedup 1.0000x reference)
//
#include <hip/hip_runtime.h>

#define HIDDEN 51
#define LSEQ 1000
#define UNROLL 8    // steps per group (x prefetch + U reload granularity)
#define UROW 105    // dwords per lane row in U-LDS; ODD => bank-conflict-free

typedef _Float16 half2_t __attribute__((ext_vector_type(2)));

#if __has_builtin(__builtin_amdgcn_fdot2)
#define FDOT2(a, b, c) __builtin_amdgcn_fdot2((a), (b), (c), false)
#else
#define FDOT2(a, b, c) fmaf((float)(a).y, (float)(b).y, \
                       fmaf((float)(a).x, (float)(b).x, (c)))
#endif

// Branch-free tanh: tanh(v) = 1 - 2/(exp2(2*log2e*v)+1). Saturates to +/-1.
__device__ __forceinline__ float fast_tanh(float v) {
    float e = __builtin_amdgcn_exp2f(v * 2.885390081777927f);  // 2*log2(e)
    float r = __builtin_amdgcn_rcpf(e + 1.0f);
    return fmaf(-2.0f, r, 1.0f);
}

template <int CTRL, int ROW_MASK>
__device__ __forceinline__ float dpp_add(float v) {
    int s = __builtin_amdgcn_update_dpp(0, __builtin_bit_cast(int, v),
                                        CTRL, ROW_MASK, 0xf, true);
    return v + __builtin_bit_cast(float, s);
}

// Full-wave sum -> lane 63 (rocPRIM gfx9 pattern). Register-only VALU.
__device__ __forceinline__ float wave_reduce_to63(float v) {
    v = dpp_add<0x111, 0xf>(v);  // row_shr:1
    v = dpp_add<0x112, 0xf>(v);  // row_shr:2
    v = dpp_add<0x114, 0xf>(v);  // row_shr:4
    v = dpp_add<0x118, 0xf>(v);  // row_shr:8
    v = dpp_add<0x142, 0xa>(v);  // row_bcast15
    v = dpp_add<0x143, 0xc>(v);  // row_bcast31
    return v;                    // lane 63 = full sum
}

// Constant-index component select of a uint4 (folds at compile time).
__device__ __forceinline__ unsigned int u4c(const uint4 v, int e) {
    return e == 0 ? v.x : e == 1 ? v.y : e == 2 ? v.z : v.w;
}

// R13: per-group U reload from an LDS staging image -> short live ranges.
// Evidence chain: busy/step ~565-606cy across ALL rounds vs ~275 ideal;
// R11 proved VOP3P can't source AGPRs (staging mandatory given AGPR
// homing); 4 compiler hints (launch_bounds/fence/"a"/waves_per_eu) all
// failed to move homing because Up's live range spans the whole loop --
// the allocator offloads the LONGEST-LIVED values to keep ~128 arch.
// Attack the live range, not the budget: stage the per-lane U image
// (104 dwords, f16 pairs, consumption order 8j+{A:g, 4+g:B}) in LDS once;
// reload per 8-step group via 104 streaming ds_read_b32 (dest = VGPR by
// construction; one-group lifetime -> nothing long-lived to offload; the
// per-step asm-"memory" fences forbid remat-reloads, pinning values in
// regs). Cost: ~75cy/step DS issue (overlaps 208cy dot issue) + ~15cy
// group-top latency + 27KB LDS (occupancy still grid-limited).
// Also: hq components consumed directly (kills R10's hw[28] copy movs).
// MFMA path evaluated & rejected: matvec wastes 15/16 of each tile;
// per-SIMD 16x16x32 ~16cy -> 26 mfma ~416cy + 2 LDS turnarounds >= today.
__global__ __attribute__((amdgpu_flat_work_group_size(64, 64),
                          amdgpu_waves_per_eu(1, 1)))
void lstm_seq_kernel(
    const float* __restrict__ x,
    const float* __restrict__ W_w,
    const float* __restrict__ W_b,
    const float* __restrict__ U_w,
    const float* __restrict__ U_b,
    const float* __restrict__ lin_w,
    const float* __restrict__ lin_b,
    float* __restrict__ out)
{
    __shared__ __attribute__((aligned(16))) _Float16 hb16[64];   // h bcast
    __shared__ unsigned int Ulds[64 * UROW];                     // 26.9 KB

    const int b    = blockIdx.x;
    const int lane = threadIdx.x;        // 0..63
    const bool active = lane < HIDDEN;   // lanes 51..63 produce exact zeros
    const int m = active ? lane : 0;

    float ww[4], bbias[4];
#pragma unroll
    for (int g = 0; g < 4; ++g) {
        const int row = m + g * HIDDEN;
        ww[g]    = active ? W_w[row] : 0.f;
        bbias[g] = active ? (W_b[row] + U_b[row]) : 0.f;
    }
    const float lw = active ? lin_w[m] : 0.f;
    const float lb = lin_b[0];

    // Stage this lane's U image to LDS as f16 k-pairs in CONSUMPTION order:
    // dot round j (0..12) consumes dwords 8j+g (A: pair j) and 8j+4+g
    // (B: pair j+13). Row stride UROW=105 (odd) => <=2-way banks (free).
    unsigned int* ul = &Ulds[lane * UROW];
#pragma unroll
    for (int j = 0; j < 13; ++j) {
#pragma unroll
        for (int g = 0; g < 4; ++g) {
            const int row = m + g * HIDDEN;
            {   // A-half: pair j  (k = 2j, 2j+1)
                const int k0 = 2 * j, k1 = k0 + 1;
                half2_t u;
                u.x = (_Float16)((active && k0 < HIDDEN) ? U_w[row * HIDDEN + k0] : 0.f);
                u.y = (_Float16)((active && k1 < HIDDEN) ? U_w[row * HIDDEN + k1] : 0.f);
                ul[8 * j + g] = __builtin_bit_cast(unsigned int, u);
            }
            {   // B-half: pair j+13  (k = 2j+26, 2j+27)
                const int k0 = 2 * (j + 13), k1 = k0 + 1;
                half2_t u;
                u.x = (_Float16)((active && k0 < HIDDEN) ? U_w[row * HIDDEN + k0] : 0.f);
                u.y = (_Float16)((active && k1 < HIDDEN) ? U_w[row * HIDDEN + k1] : 0.f);
                ul[8 * j + 4 + g] = __builtin_bit_cast(unsigned int, u);
            }
        }
    }

    float h = 0.f, c = 0.f;
    const float* __restrict__ xrow = x + (long)b * LSEQ;
    float* __restrict__ orow = out + (long)b * LSEQ;

    hb16[lane] = (_Float16)0.f;
    __builtin_amdgcn_wave_barrier();
    asm volatile("" ::: "memory");        // init stores precede all reads

    // NO restrict: hb16 reads must be assumed to alias its stores (R9 bug).
    const uint4* hbv = (const uint4*)hb16;  // 8 f16 per b128 read

    // Prologue: group 0's x resident before the loop.
    float xg[UNROLL];
#pragma unroll
    for (int s = 0; s < UNROLL; ++s) xg[s] = xrow[s];

    for (int T = 0; T < LSEQ; T += UNROLL) {
        // Prefetch NEXT group's x; consumed next iteration.
        const int Tn = (T + UNROLL < LSEQ) ? (T + UNROLL) : 0;
        float xn[UNROLL];
#pragma unroll
        for (int s = 0; s < UNROLL; ++s) xn[s] = xrow[Tn + s];

        // Reload this lane's U image: 104 streaming ds_read_b32.
        // Fresh one-group lifetime => VGPR-resident by construction.
        unsigned int ur[104];
#pragma unroll
        for (int i = 0; i < 104; ++i) ur[i] = ul[i];

        float rsum[UNROLL];
#pragma unroll
        for (int s = 0; s < UNROLL; ++s) {
            // 7 same-address b128 broadcasts; components consumed
            // DIRECTLY (no unpack-copy array).
            uint4 hq[7];
#pragma unroll
            for (int q = 0; q < 7; ++q) hq[q] = hbv[q];

            // 8 independent dot2 chains: gate g x {A: pairs 0-12,
            // B: pairs 13-25}. A seeded with x*W + (W_b+U_b), B with 0.
            float aA[4], aB[4];
#pragma unroll
            for (int g = 0; g < 4; ++g) {
                aA[g] = fmaf(xg[s], ww[g], bbias[g]);
                aB[g] = 0.f;
            }
#pragma unroll
            for (int j = 0; j < 13; ++j) {
                const int jb = j + 13;
                const half2_t hpA = __builtin_bit_cast(half2_t, u4c(hq[j  >> 2], j  & 3));
                const half2_t hpB = __builtin_bit_cast(half2_t, u4c(hq[jb >> 2], jb & 3));
#pragma unroll
                for (int g = 0; g < 4; ++g) {
                    aA[g] = FDOT2(hpA, __builtin_bit_cast(half2_t, ur[8 * j + g]),     aA[g]);
                    aB[g] = FDOT2(hpB, __builtin_bit_cast(half2_t, ur[8 * j + 4 + g]), aB[g]);
                }
            }
            const float gi = aA[0] + aB[0];
            const float gf = aA[1] + aB[1];
            const float gg = aA[2] + aB[2];
            const float go = aA[3] + aB[3];

            // NOTE: faithful to reference -- no sigmoid on gates.
            c = fmaf(gf, c, gi * gg);
            h = go * fast_tanh(c);        // inactive lanes stay exactly 0

            __builtin_amdgcn_wave_barrier();
            asm volatile("" ::: "memory");    // reads above precede store
            hb16[lane] = (_Float16)h;         // 2B store; recurrence fp32
            __builtin_amdgcn_wave_barrier();
            asm volatile("" ::: "memory");    // store precedes next reads

            // Projection reduce in the broadcast-read shadow.
            rsum[s] = wave_reduce_to63(h * lw);
        }

        if (lane == 63) {
            float4 o0 = {rsum[0] + lb, rsum[1] + lb, rsum[2] + lb, rsum[3] + lb};
            float4 o1 = {rsum[4] + lb, rsum[5] + lb, rsum[6] + lb, rsum[7] + lb};
            *(float4*)&orow[T]     = o0;   // orow 16B-aligned (b*4000 bytes)
            *(float4*)&orow[T + 4] = o1;
        }

#pragma unroll
        for (int s = 0; s < UNROLL; ++s) xg[s] = xn[s];  // rotate buffers
    }
}

extern "C" void kernel_launch(void* const* d_in, const int* in_sizes, int n_in,
                              void* d_out, int out_size, void* d_ws, size_t ws_size,
                              hipStream_t stream) {
    const float* x     = (const float*)d_in[0];
    const float* W_w   = (const float*)d_in[1];
    const float* W_b   = (const float*)d_in[2];
    const float* U_w   = (const float*)d_in[3];
    const float* U_b   = (const float*)d_in[4];
    const float* lin_w = (const float*)d_in[5];
    const float* lin_b = (const float*)d_in[6];
    // d_in[7] = future (static 0; out_size == B*LSEQ)
    float* out = (float*)d_out;

    const int B = in_sizes[0] / LSEQ;  // 1024
    lstm_seq_kernel<<<dim3(B), dim3(64), 0, stream>>>(
        x, W_w, W_b, U_w, U_b, lin_w, lin_b, out);
}